// Round 7
// baseline (207.078 us; speedup 1.0000x reference)
//
#include <hip/hip_runtime.h>
#include <math.h>

#define WNUM 1792
#define HID 128

#define INV3C 0.5773502691896258f
#define INV2C 0.7071067811865476f
#define A0C   0.17677669529663687f   /* 1/sqrt(32) */
#define A1C   0.14433756729740643f   /* 1/sqrt(48) */
#define MAXDEG 64

typedef short bf8 __attribute__((ext_vector_type(8)));
typedef _Float16 f16x8 __attribute__((ext_vector_type(8)));
typedef _Float16 f16x4 __attribute__((ext_vector_type(4)));
typedef float f32x4 __attribute__((ext_vector_type(4)));

__device__ inline unsigned short f2bf(float f) {
  union { float f; unsigned u; } v; v.f = f;
  unsigned r = v.u + 0x7FFFu + ((v.u >> 16) & 1u);   // RNE
  return (unsigned short)(r >> 16);
}
__device__ inline float bf2f(unsigned short h) {
  union { unsigned u; float f; } v; v.u = ((unsigned)h) << 16;
  return v.f;
}
__device__ inline float wscale(int t) {
  if (t < 32) return A0C;
  if (t < 64) return A0C * INV3C;
  if (t < 96) return A1C;
  return A1C * INV2C;
}

// ---- prep: weight staging + cnt zeroing (layouts unchanged) ----
__global__ __launch_bounds__(256) void prep_kernel(
    const float* __restrict__ We1, const float* __restrict__ We2,
    const float* __restrict__ be2,
    unsigned short* __restrict__ we1x, _Float16* __restrict__ we2h,
    float* __restrict__ be2p, int* __restrict__ cntp, int N)
{
  int i = blockIdx.x * 256 + threadIdx.x;
  if (i < 28672) {
    int t = i >> 8, c = (i >> 6) & 3, lane = i & 63;
    int quad = lane >> 4, l15 = lane & 15;
    int col = t * 16 + l15;
    float sc = wscale(t);
    f16x8 v;
    #pragma unroll
    for (int j = 0; j < 8; ++j) {
      int k = c * 32 + quad * 8 + j;
      v[j] = (_Float16)(We2[(size_t)k * WNUM + col] * sc);
    }
    *(f16x8*)(we2h + (size_t)t * 2048 + c * 512 + lane * 8) = v;
  } else if (i < 29184) {
    int q = i - 28672;
    int c1 = q >> 6, lane = q & 63;
    int quad = lane >> 4, l15 = lane & 15;
    int col = c1 * 16 + l15;
    bf8 hh, ll;
    #pragma unroll
    for (int j = 0; j < 8; ++j) {
      int k = quad * 8 + j;
      float v = We1[k * HID + col];
      unsigned short hi = f2bf(v);
      hh[j] = (short)hi;
      ll[j] = (short)f2bf(v - bf2f(hi));
    }
    *(bf8*)(we1x + c1 * 1024 + lane * 8) = hh;
    *(bf8*)(we1x + c1 * 1024 + 512 + lane * 8) = ll;
  } else if (i < 30976) {
    int q = i - 29184;
    int t = q >> 4, l16 = q & 15;
    be2p[(t >> 1) * 32 + l16 * 2 + (t & 1)] = be2[q] * wscale(t);
  } else if (i < 30976 + N) {
    cntp[i - 30976] = 0;
  }
}

// ---- fused edge kernel: 4 waves x 32 edges, zero barriers ----
// B prefetched through a wave-private LDS double-buffer at 16-col TILE
// granularity (2048 f16 = 4 KB = one slot; 112 tiles total). In-flight data
// costs zero arch VGPRs (round-5: the arch-VGPR cap at launch_bounds(256,2)
// is 128; register dbuf spilled). Round-6 bug: slots were sized for a tile
// but staged/read as 8 KB pairs -> cross-slot/cross-wave corruption; fixed
// by making the pipeline unit = tile.
// Per tile t: 4x ds_read_b128 (slot t&1) -> lgkmcnt(0) [slot drained, WAR]
// -> stage tile t+2 into that slot (4x global_load_lds) -> 8 MFMA + contract
// -> vmcnt(4) [tile t+1 arrived; only t+2's 4 loads outstanding].
// Biases live in a block-shared LDS f16 table (identical redundant writes
// per wave); s2/v2 broadcasts are direct sh[] loads at section boundaries
// (extra vm ops only make vmcnt(4) over-wait - safe).
// LDS 52,736 B -> 3 blocks/CU.
template <bool MSG>
__global__ __launch_bounds__(256, 2) void edge_kernel(
    const float* __restrict__ ea, const float* __restrict__ xsrc,
    const float* __restrict__ sh, const int* __restrict__ dst,
    const float* __restrict__ be1,
    const unsigned short* __restrict__ we1x, const _Float16* __restrict__ we2h,
    const float* __restrict__ be2p,
    float* __restrict__ outp, int* __restrict__ eidx, int* __restrict__ cntp, int E)
{
  const int lane = threadIdx.x & 63;
  const int w    = threadIdx.x >> 6;     // 0..3
  const int quad = lane >> 4;
  const int l16  = lane & 15;
  const int eb   = (blockIdx.x * 4 + w) * 32;

  // per-wave union: h transpose staging (preamble) / B tile double-buffer
  __shared__ union WaveMem {
    _Float16 h[16][136];      // 4,352 B
    _Float16 B[2][2048];      // 8,192 B (2 tiles x 4 KB)
  } uw[4];                                     // 32,768 B
  __shared__ _Float16 s1h_s[4][16][32];        //  4,096 B
  __shared__ _Float16 v1h_s[4][16][3][32];     // 12,288 B
  __shared__ _Float16 biasL[1792];             //  3,584 B (be2p as f16)

  #define STAGE_H(h_) { \
    const _Float16* gsrc_ = we2h + (size_t)(h_) * 2048; \
    _Float16* ldst_ = &uw[w].B[(h_) & 1][0]; \
    _Pragma("unroll") \
    for (int k_ = 0; k_ < 4; ++k_) \
      __builtin_amdgcn_global_load_lds( \
        (const __attribute__((address_space(1))) void*)(gsrc_ + k_ * 512 + lane * 8), \
        (__attribute__((address_space(3))) void*)(ldst_ + k_ * 512), 16, 0, 0); \
  }
  #define FENCE_LGKM { asm volatile("s_waitcnt lgkmcnt(0)" ::: "memory"); \
                       __builtin_amdgcn_sched_barrier(0); }
  #define FENCE_VM4  { asm volatile("s_waitcnt vmcnt(4)" ::: "memory"); \
                       __builtin_amdgcn_sched_barrier(0); }
  #define FENCE_VM0  { asm volatile("s_waitcnt vmcnt(0)" ::: "memory"); \
                       __builtin_amdgcn_sched_barrier(0); }

  // one 16-col tile: 4 ds_reads -> drain -> prefetch t+2 -> 8 MFMA ->
  // contraction (__VA_ARGS__, sees w0 [g=0] and w1 [g=1]) -> vm fence
  #define TILE(t_, ...) { \
    const _Float16* bL_ = &uw[w].B[(t_) & 1][lane * 8]; \
    f16x8 b0_ = *(const f16x8*)(bL_); \
    f16x8 b1_ = *(const f16x8*)(bL_ + 512); \
    f16x8 b2_ = *(const f16x8*)(bL_ + 1024); \
    f16x8 b3_ = *(const f16x8*)(bL_ + 1536); \
    float bs_ = (float)biasL[((t_) >> 1) * 32 + l16 * 2 + ((t_) & 1)]; \
    FENCE_LGKM \
    if ((t_) + 2 < 112) { STAGE_H((t_) + 2) __builtin_amdgcn_sched_barrier(0); } \
    f32x4 w0 = {bs_, bs_, bs_, bs_}, w1 = w0; \
    w0 = __builtin_amdgcn_mfma_f32_16x16x32_f16(af[0][0], b0_, w0, 0, 0, 0); \
    w1 = __builtin_amdgcn_mfma_f32_16x16x32_f16(af[1][0], b0_, w1, 0, 0, 0); \
    w0 = __builtin_amdgcn_mfma_f32_16x16x32_f16(af[0][1], b1_, w0, 0, 0, 0); \
    w1 = __builtin_amdgcn_mfma_f32_16x16x32_f16(af[1][1], b1_, w1, 0, 0, 0); \
    w0 = __builtin_amdgcn_mfma_f32_16x16x32_f16(af[0][2], b2_, w0, 0, 0, 0); \
    w1 = __builtin_amdgcn_mfma_f32_16x16x32_f16(af[1][2], b2_, w1, 0, 0, 0); \
    w0 = __builtin_amdgcn_mfma_f32_16x16x32_f16(af[0][3], b3_, w0, 0, 0, 0); \
    w1 = __builtin_amdgcn_mfma_f32_16x16x32_f16(af[1][3], b3_, w1, 0, 0, 0); \
    { __VA_ARGS__ } \
    if ((t_) + 2 < 112) { FENCE_VM4 } else { FENCE_VM0 } \
  }

  // slot-fill / count early
  if (lane < 32) {
    int ge = eb + lane;
    if (ge < E) {
      int node = dst[ge];
      int pos = atomicAdd(cntp + node, 1);
      if (MSG) { if (pos < MAXDEG) eidx[node * MAXDEG + pos] = ge; }
    }
  }

  // bias table -> LDS (each wave writes the full table; identical values)
  {
    int base = lane * 28;
    #pragma unroll
    for (int k = 0; k < 28; ++k)
      biasL[base + k] = (_Float16)be2p[base + k];
  }

  // ---- stage per-edge factors (wave-private) ----
  {
    int e2 = lane >> 1, mg = lane & 1;
    int ge = eb + e2;
    if (ge < E) {
      const float* xp = xsrc + (size_t)ge * 64;
      float4 sq0 = *(const float4*)(xp + mg * 8);
      float4 sq1 = *(const float4*)(xp + mg * 8 + 4);
      float s1a[8] = {sq0.x,sq0.y,sq0.z,sq0.w,sq1.x,sq1.y,sq1.z,sq1.w};
      const float* vp = xp + 16 + mg * 24;
      float la[24];
      #pragma unroll
      for (int qv = 0; qv < 6; ++qv) {
        float4 t = *(const float4*)(vp + qv * 4);
        la[qv*4+0] = t.x; la[qv*4+1] = t.y; la[qv*4+2] = t.z; la[qv*4+3] = t.w;
      }
      #pragma unroll
      for (int mi = 0; mi < 8; ++mi) {
        int m = mg * 8 + mi;
        s1h_s[w][m][e2] = (_Float16)s1a[mi];
        v1h_s[w][m][0][e2] = (_Float16)la[mi*3];
        v1h_s[w][m][1][e2] = (_Float16)la[mi*3+1];
        v1h_s[w][m][2][e2] = (_Float16)la[mi*3+2];
      }
    } else {
      #pragma unroll
      for (int mi = 0; mi < 8; ++mi) {
        int m = mg * 8 + mi;
        s1h_s[w][m][e2] = (_Float16)0.f;
        v1h_s[w][m][0][e2] = (_Float16)0.f;
        v1h_s[w][m][1][e2] = (_Float16)0.f;
        v1h_s[w][m][2][e2] = (_Float16)0.f;
      }
    }
  }

  // ---- layer 1 + A-fragment extraction (wave-local, uses uw[w].h) ----
  f16x8 af[2][4];
  {
    const unsigned short* wb1 = we1x + lane * 8;
    #pragma unroll
    for (int g = 0; g < 2; ++g) {
      bf8 ah, al;
      {
        int gea = eb + g * 16 + l16; if (gea > E - 1) gea = E - 1;
        const float* ep = ea + (size_t)gea * 32 + quad * 8;
        float4 p0 = *(const float4*)ep;
        float4 p1 = *(const float4*)(ep + 4);
        float pv[8] = {p0.x,p0.y,p0.z,p0.w,p1.x,p1.y,p1.z,p1.w};
        #pragma unroll
        for (int j = 0; j < 8; ++j) {
          unsigned short hi = f2bf(pv[j]);
          ah[j] = (short)hi;
          al[j] = (short)f2bf(pv[j] - bf2f(hi));
        }
      }
      #pragma unroll 2
      for (int c = 0; c < 8; ++c) {
        bf8 bh = *(const bf8*)(wb1 + c * 1024);
        bf8 bl = *(const bf8*)(wb1 + c * 1024 + 512);
        float bias = be1[c * 16 + l16];
        f32x4 hc = {bias, bias, bias, bias};
        hc = __builtin_amdgcn_mfma_f32_16x16x32_bf16(al, bh, hc, 0, 0, 0);
        hc = __builtin_amdgcn_mfma_f32_16x16x32_bf16(ah, bl, hc, 0, 0, 0);
        hc = __builtin_amdgcn_mfma_f32_16x16x32_bf16(ah, bh, hc, 0, 0, 0);
        #pragma unroll
        for (int r = 0; r < 4; ++r)
          uw[w].h[quad * 4 + r][c * 16 + l16] = (_Float16)fmaxf(hc[r], 0.f);
      }
      #pragma unroll
      for (int ch = 0; ch < 4; ++ch)
        af[g][ch] = *(const f16x8*)&uw[w].h[l16][ch * 32 + quad * 8];
      // WAR: next round's h-writes / B staging must not pass these reads
      FENCE_LGKM
    }
  }

  // s2 broadcast for section 1 (direct from sh, clamped)
  float s2v[2][4];
  #pragma unroll
  for (int g = 0; g < 2; ++g)
    #pragma unroll
    for (int r = 0; r < 4; ++r) {
      int gev = eb + g * 16 + quad * 4 + r; if (gev > E - 1) gev = E - 1;
      s2v[g][r] = sh[(size_t)gev * 4];
    }

  // prologue: stage tiles 0,1; wait tile 0 arrived (tile 1's 4 may fly)
  STAGE_H(0)
  STAGE_H(1)
  FENCE_VM4

  float m0a[2][4] = {{0,0,0,0},{0,0,0,0}}, m0b[2][4] = {{0,0,0,0},{0,0,0,0}};

  // ---- section 1: ss (tiles 0..31, channel i = t>>1); fss = s1*s2 ----
  #pragma unroll 1
  for (int i = 0; i < 16; ++i) {
    float fA[4], fB[4];
    {
      f16x4 fv0 = *(const f16x4*)&s1h_s[w][i][quad * 4];
      f16x4 fv1 = *(const f16x4*)&s1h_s[w][i][16 + quad * 4];
      for (int r = 0; r < 4; ++r) {
        fA[r] = (float)fv0[r] * s2v[0][r];
        fB[r] = (float)fv1[r] * s2v[1][r];
      }
    }
    TILE(2 * i,
      for (int r = 0; r < 4; ++r) {
        m0a[0][r] = fmaf(w0[r], fA[r], m0a[0][r]);
        m0a[1][r] = fmaf(w1[r], fB[r], m0a[1][r]);
      }
    )
    TILE(2 * i + 1,
      for (int r = 0; r < 4; ++r) {
        m0b[0][r] = fmaf(w0[r], fA[r], m0b[0][r]);
        m0b[1][r] = fmaf(w1[r], fB[r], m0b[1][r]);
      }
    )
  }

  // ---- section 2: vv0 (tiles 32..63, channel i); fvv = v1·v2 ----
  {
    float v2xv[2][4], v2yv[2][4], v2zv[2][4];
    #pragma unroll
    for (int g = 0; g < 2; ++g)
      #pragma unroll
      for (int r = 0; r < 4; ++r) {
        int gev = eb + g * 16 + quad * 4 + r; if (gev > E - 1) gev = E - 1;
        const float* sp = sh + (size_t)gev * 4;
        v2xv[g][r] = sp[1]; v2yv[g][r] = sp[2]; v2zv[g][r] = sp[3];
      }

    #pragma unroll 1
    for (int i = 0; i < 16; ++i) {
      float fA[4], fB[4];
      {
        f16x4 x0 = *(const f16x4*)&v1h_s[w][i][0][quad * 4];
        f16x4 y0 = *(const f16x4*)&v1h_s[w][i][1][quad * 4];
        f16x4 z0 = *(const f16x4*)&v1h_s[w][i][2][quad * 4];
        f16x4 x1 = *(const f16x4*)&v1h_s[w][i][0][16 + quad * 4];
        f16x4 y1 = *(const f16x4*)&v1h_s[w][i][1][16 + quad * 4];
        f16x4 z1 = *(const f16x4*)&v1h_s[w][i][2][16 + quad * 4];
        for (int r = 0; r < 4; ++r) {
          fA[r] = fmaf((float)z0[r], v2zv[0][r],
                  fmaf((float)y0[r], v2yv[0][r], (float)x0[r] * v2xv[0][r]));
          fB[r] = fmaf((float)z1[r], v2zv[1][r],
                  fmaf((float)y1[r], v2yv[1][r], (float)x1[r] * v2xv[1][r]));
        }
      }
      TILE(32 + 2 * i,
        for (int r = 0; r < 4; ++r) {
          m0a[0][r] = fmaf(w0[r], fA[r], m0a[0][r]);
          m0a[1][r] = fmaf(w1[r], fB[r], m0a[1][r]);
        }
      )
      TILE(33 + 2 * i,
        for (int r = 0; r < 4; ++r) {
          m0b[0][r] = fmaf(w0[r], fA[r], m0b[0][r]);
          m0b[1][r] = fmaf(w1[r], fB[r], m0b[1][r]);
        }
      )
    }
  }

  // ---- emit out0 (stores join the vm stream; fences are count-safe) ----
  #pragma unroll
  for (int g = 0; g < 2; ++g)
    #pragma unroll
    for (int r = 0; r < 4; ++r) {
      int ge = eb + g * 16 + quad * 4 + r;
      if (ge < E) {
        if (MSG) {
          float* mp = outp + (size_t)ge * 80;
          mp[l16]      = m0a[g][r];
          mp[16 + l16] = m0b[g][r];
        } else {
          float* ap = outp + (size_t)dst[ge] * 80;
          atomicAdd(ap + l16,      m0a[g][r]);
          atomicAdd(ap + 16 + l16, m0b[g][r]);
        }
      }
    }

  // vq broadcast for sections 3-5 / epilogue: q = (s2, v2x, v2y, v2z)
  float4 vq[2][4];
  #pragma unroll
  for (int g = 0; g < 2; ++g)
    #pragma unroll
    for (int r = 0; r < 4; ++r) {
      int gev = eb + g * 16 + quad * 4 + r; if (gev > E - 1) gev = E - 1;
      vq[g][r] = *(const float4*)(sh + (size_t)gev * 4);
    }

  // ---- section 3: sv (tiles 64..79, channel = t-64) ----
  float sg[2][4] = {{0,0,0,0},{0,0,0,0}};
  #pragma unroll 1
  for (int ch = 0; ch < 16; ++ch) {
    f16x4 s0 = *(const f16x4*)&s1h_s[w][ch][quad * 4];
    f16x4 s1f = *(const f16x4*)&s1h_s[w][ch][16 + quad * 4];
    TILE(64 + ch,
      for (int r = 0; r < 4; ++r) {
        sg[0][r] = fmaf(w0[r], (float)s0[r], sg[0][r]);
        sg[1][r] = fmaf(w1[r], (float)s1f[r], sg[1][r]);
      }
    )
  }

  float m1x[2][4], m1y[2][4], m1z[2][4];
  #pragma unroll
  for (int g = 0; g < 2; ++g)
    #pragma unroll
    for (int r = 0; r < 4; ++r) {
      m1x[g][r] = sg[g][r] * vq[g][r].y;   // v2x
      m1y[g][r] = sg[g][r] * vq[g][r].z;   // v2y
      m1z[g][r] = sg[g][r] * vq[g][r].w;   // v2z
    }

  // ---- sections 4+5: vs (tiles 80..95) then vv1 (96..111), ch = local t ----
  #pragma unroll
  for (int sec = 0; sec < 2; ++sec) {
    float ux[2][4] = {{0,0,0,0},{0,0,0,0}}, uy[2][4] = {{0,0,0,0},{0,0,0,0}},
          uz[2][4] = {{0,0,0,0},{0,0,0,0}};
    int tb = 80 + sec * 16;
    #pragma unroll 1
    for (int ch = 0; ch < 16; ++ch) {
      f16x4 xA = *(const f16x4*)&v1h_s[w][ch][0][quad * 4];
      f16x4 yA = *(const f16x4*)&v1h_s[w][ch][1][quad * 4];
      f16x4 zA = *(const f16x4*)&v1h_s[w][ch][2][quad * 4];
      f16x4 xB = *(const f16x4*)&v1h_s[w][ch][0][16 + quad * 4];
      f16x4 yB = *(const f16x4*)&v1h_s[w][ch][1][16 + quad * 4];
      f16x4 zB = *(const f16x4*)&v1h_s[w][ch][2][16 + quad * 4];
      TILE(tb + ch,
        for (int r = 0; r < 4; ++r) {
          ux[0][r] = fmaf(w0[r], (float)xA[r], ux[0][r]);
          ux[1][r] = fmaf(w1[r], (float)xB[r], ux[1][r]);
          uy[0][r] = fmaf(w0[r], (float)yA[r], uy[0][r]);
          uy[1][r] = fmaf(w1[r], (float)yB[r], uy[1][r]);
          uz[0][r] = fmaf(w0[r], (float)zA[r], uz[0][r]);
          uz[1][r] = fmaf(w1[r], (float)zB[r], uz[1][r]);
        }
      )
    }
    if (sec == 0) {
      #pragma unroll
      for (int g = 0; g < 2; ++g)
        #pragma unroll
        for (int r = 0; r < 4; ++r) {
          m1x[g][r] = fmaf(vq[g][r].x, ux[g][r], m1x[g][r]);   // s2
          m1y[g][r] = fmaf(vq[g][r].x, uy[g][r], m1y[g][r]);
          m1z[g][r] = fmaf(vq[g][r].x, uz[g][r], m1z[g][r]);
        }
    } else {
      #pragma unroll
      for (int g = 0; g < 2; ++g)
        #pragma unroll
        for (int r = 0; r < 4; ++r) {
          m1x[g][r] = fmaf(uy[g][r], vq[g][r].w, m1x[g][r]);   // uy*v2z
          m1x[g][r] = fmaf(-uz[g][r], vq[g][r].z, m1x[g][r]);  // -uz*v2y
          m1y[g][r] = fmaf(uz[g][r], vq[g][r].y, m1y[g][r]);   // uz*v2x
          m1y[g][r] = fmaf(-ux[g][r], vq[g][r].w, m1y[g][r]);  // -ux*v2z
          m1z[g][r] = fmaf(ux[g][r], vq[g][r].z, m1z[g][r]);   // ux*v2y
          m1z[g][r] = fmaf(-uy[g][r], vq[g][r].y, m1z[g][r]);  // -uy*v2x
        }
    }
  }

  // ---- emit out1 ----
  #pragma unroll
  for (int g = 0; g < 2; ++g)
    #pragma unroll
    for (int r = 0; r < 4; ++r) {
      int ge = eb + g * 16 + quad * 4 + r;
      if (ge < E) {
        if (MSG) {
          float* mp = outp + (size_t)ge * 80;
          mp[32 + l16*3 + 0] = m1x[g][r];
          mp[32 + l16*3 + 1] = m1y[g][r];
          mp[32 + l16*3 + 2] = m1z[g][r];
        } else {
          float* ap = outp + (size_t)dst[ge] * 80;
          atomicAdd(ap + 32 + l16*3 + 0, m1x[g][r]);
          atomicAdd(ap + 32 + l16*3 + 1, m1y[g][r]);
          atomicAdd(ap + 32 + l16*3 + 2, m1z[g][r]);
        }
      }
    }
  #undef TILE
  #undef STAGE_H
  #undef FENCE_LGKM
  #undef FENCE_VM4
  #undef FENCE_VM0
}

// ---- node gather (MSG path) ----
__global__ __launch_bounds__(128) void node_gather_kernel(
    const float* __restrict__ msg, const int* __restrict__ eidx,
    const int* __restrict__ cntp,
    const float* __restrict__ xdst, const float* __restrict__ Wr0,
    const float* __restrict__ Wr1, float* __restrict__ out, int N)
{
  int n = blockIdx.x;
  if (n >= N) return;
  int j = threadIdx.x;
  int c0 = cntp[n];
  int deg = c0 < MAXDEG ? c0 : MAXDEG;
  float inv = 1.0f / fmaxf((float)c0, 1.0f);
  __shared__ float s_sum[80];
  if (j < 80) {
    float s = 0.f;
    const int* ep = eidx + (size_t)n * MAXDEG;
    int i = 0;
    for (; i + 1 < deg; i += 2) {
      int e0 = ep[i], e1 = ep[i + 1];
      s += msg[(size_t)e0 * 80 + j] + msg[(size_t)e1 * 80 + j];
    }
    if (i < deg) s += msg[(size_t)ep[i] * 80 + j];
    s_sum[j] = s * inv;
  }
  __syncthreads();
  if (j >= 64) return;
  const float* xd = xdst + (size_t)n * 64;
  float* op = out + (size_t)n * 64;
  if (j < 16) {
    float s = 0.f;
    #pragma unroll
    for (int m = 0; m < 16; ++m) s = fmaf(xd[m], Wr0[m * 32 + j], s);
    op[j] = fmaxf(s_sum[j] + 0.25f * s, 0.f);
  } else {
    int jj = j - 16;
    int o = (jj * 86) >> 8;
    int c = jj - o * 3;
    float tg = 0.f, v = 0.f;
    #pragma unroll
    for (int m = 0; m < 16; ++m) {
      tg = fmaf(xd[m], Wr0[m * 32 + 16 + o], tg);
      v  = fmaf(xd[16 + m * 3 + c], Wr1[m * 16 + o], v);
    }
    float g = 1.0f / (1.0f + expf(-(s_sum[16 + o] + 0.25f * tg)));
    op[16 + jj] = (s_sum[32 + jj] + 0.25f * v) * g;
  }
}

// ---- node epilogue (atomic fallback path) ----
__global__ __launch_bounds__(256) void node_kernel(
    const float* __restrict__ accn, const int* __restrict__ cntp,
    const float* __restrict__ xdst, const float* __restrict__ Wr0,
    const float* __restrict__ Wr1, float* __restrict__ out, int N)
{
  int idx = blockIdx.x * 256 + threadIdx.x;
  int n = idx >> 6, j = idx & 63;
  if (n >= N) return;
  float inv = 1.0f / fmaxf((float)cntp[n], 1.0f);
  const float* ap = accn + (size_t)n * 80;
  const float* xd = xdst + (size_t)n * 64;
  float* op = out + (size_t)n * 64;
  if (j < 16) {
    float s = 0.f;
    #pragma unroll
    for (int m = 0; m < 16; ++m) s = fmaf(xd[m], Wr0[m * 32 + j], s);
    op[j] = fmaxf(ap[j] * inv + 0.25f * s, 0.f);
  } else {
    int jj = j - 16;
    int o = (jj * 86) >> 8;
    int c = jj - o * 3;
    float tg = 0.f, v = 0.f;
    #pragma unroll
    for (int m = 0; m < 16; ++m) {
      tg = fmaf(xd[m], Wr0[m * 32 + 16 + o], tg);
      v  = fmaf(xd[16 + m * 3 + c], Wr1[m * 16 + o], v);
    }
    float g = 1.0f / (1.0f + expf(-(ap[16 + o] * inv + 0.25f * tg)));
    op[16 + jj] = (ap[32 + jj] * inv + 0.25f * v) * g;
  }
}

extern "C" void kernel_launch(void* const* d_in, const int* in_sizes, int n_in,
                              void* d_out, int out_size, void* d_ws, size_t ws_size,
                              hipStream_t stream)
{
  const int*   dst  = (const int*)d_in[0];
  const float* xsrc = (const float*)d_in[1];
  const float* xdst = (const float*)d_in[2];
  const float* sh   = (const float*)d_in[3];
  const float* ea   = (const float*)d_in[4];
  const float* We1  = (const float*)d_in[5];
  const float* be1  = (const float*)d_in[6];
  const float* We2  = (const float*)d_in[7];
  const float* be2  = (const float*)d_in[8];
  const float* Wr0  = (const float*)d_in[9];
  const float* Wr1  = (const float*)d_in[10];
  const int E = in_sizes[0];
  const int N = in_sizes[2] / 64;

  char* ws = (char*)d_ws;
  _Float16* we2h = (_Float16*)ws;                           // 458,752 B
  unsigned short* we1x = (unsigned short*)(ws + 458752);    //  16,384 B
  float* be2p = (float*)(ws + 475136);                      //   7,424 B
  int*   cntp = (int*)(ws + 482560);                        // N*4
  size_t off = 482560 + (size_t)N * 4;
  off = (off + 15) & ~(size_t)15;

  size_t need_msg = off + (size_t)N * MAXDEG * 4 + (size_t)E * 80 * 4;
  bool use_msg = (ws_size >= need_msg);

  prep_kernel<<<(30976 + N + 255) / 256, 256, 0, stream>>>(We1, We2, be2,
      we1x, we2h, be2p, cntp, N);

  if (use_msg) {
    int* eidx = (int*)(ws + off);
    float* msg = (float*)(ws + off + (size_t)N * MAXDEG * 4);
    edge_kernel<true><<<(E + 127) / 128, 256, 0, stream>>>(ea, xsrc, sh, dst, be1,
        we1x, we2h, be2p, msg, eidx, cntp, E);
    node_gather_kernel<<<N, 128, 0, stream>>>(msg, eidx, cntp, xdst, Wr0, Wr1,
        (float*)d_out, N);
  } else {
    float* accn = (float*)(ws + off);
    hipMemsetAsync(accn, 0, (size_t)N * 320, stream);
    edge_kernel<false><<<(E + 127) / 128, 256, 0, stream>>>(ea, xsrc, sh, dst, be1,
        we1x, we2h, be2p, accn, (int*)nullptr, cntp, E);
    node_kernel<<<((size_t)N * 64 + 255) / 256, 256, 0, stream>>>(accn, cntp,
        xdst, Wr0, Wr1, (float*)d_out, N);
  }
}